// Round 9
// baseline (432.506 us; speedup 1.0000x reference)
//
#include <hip/hip_runtime.h>
#include <hip/hip_bf16.h>

#define N_ENT 4096
#define N_REL 4
#define FDIM 128
#define KDIM 512      // N_REL * FDIM
#define MAXNZ 128     // binomial(4096,0.01): mean 41, std 6.4; 128 is >13 sigma
#define BATCH 8192
#define NROWS (N_REL * N_ENT)

typedef float f4v __attribute__((ext_vector_type(4)));

// ---------------------------------------------------------------------------
// K_sparse: PURE adj stream kernel.
// R8 single-variable experiment (resubmitted after infra failure): adj loads
// are PLAIN (no nontemporal hint).
//   Rationale: adj is a 256MB INPUT (never re-poisoned; only the workspace
//   gets the 1GiB fill each iteration). R3's counters showed 90MB of adj
//   served from L3 even WITH the NT hint (FETCH 167MB < 256MB). NT bypasses
//   cache allocation -> blocks cross-iteration L3 residency. Plain loads let
//   the Infinity Cache retain the stream. (R5 bundled this with a gather
//   change and regressed; this isolates it properly.)
//   blocks [0, NROWS): sparsify one adj row: coalesced wave-contiguous
//     float4 loads, popc -> 6-step shfl_up scan -> direct global cols writes.
//   blocks [NROWS, NROWS+514): W1/W2 transpose + relmat diag extract.
// ---------------------------------------------------------------------------
__global__ __launch_bounds__(256) void k_sparse(
    const float* __restrict__ W1, const float* __restrict__ W2,
    const float* __restrict__ M, const float* __restrict__ adj,
    float* __restrict__ W1T, float* __restrict__ W2T, float* __restrict__ diagM,
    unsigned short* __restrict__ cols, int* __restrict__ cnt,
    float* __restrict__ inv_deg) {
  int blk = blockIdx.x;
  if (blk < NROWS) {
    int row = blk;               // r*N_ENT + n
    __shared__ int wtot[4];
    int w = threadIdx.x >> 6;    // wave 0..3, owns elements [w*1024, w*1024+1024)
    int l = threadIdx.x & 63;    // lane
    const f4v* rowp = (const f4v*)(adj + (size_t)row * N_ENT);
    unsigned mask = 0;
#pragma unroll
    for (int q = 0; q < 4; ++q) {
      // float4 index w*256 + q*64 + l: lanes consecutive -> 1 KB/wave/load
      f4v v = rowp[w * 256 + q * 64 + l];          // PLAIN load (R8: was NT)
      if (v.x != 0.f) mask |= 1u << (q * 4 + 0);
      if (v.y != 0.f) mask |= 1u << (q * 4 + 1);
      if (v.z != 0.f) mask |= 1u << (q * 4 + 2);
      if (v.w != 0.f) mask |= 1u << (q * 4 + 3);
    }
    int my = __popc(mask);
    // wave-inclusive prefix scan of per-lane counts (6 shfl_up steps)
    int scan = my;
#pragma unroll
    for (int off = 1; off < 64; off <<= 1) {
      int nb = __shfl_up(scan, off, 64);
      if (l >= off) scan += nb;
    }
    if (l == 63) wtot[w] = scan;       // wave total
    int excl = scan - my;              // lane-exclusive prefix within wave
    __syncthreads();
    int wbase = 0, c = 0;
#pragma unroll
    for (int ww = 0; ww < 4; ++ww) {
      int t = wtot[ww];
      if (ww < w) wbase += t;
      c += t;
    }
    if (c > MAXNZ) c = MAXNZ;
    int p = wbase + excl;
    unsigned m = mask;
    unsigned short* cp = cols + (size_t)row * MAXNZ;
    while (m) {
      int b = __ffs(m) - 1;
      m &= m - 1;
      int col = w * 1024 + (b >> 2) * 256 + l * 4 + (b & 3);
      if (p < MAXNZ) cp[p] = (unsigned short)col;
      ++p;
    }
    if (threadIdx.x == 0) {
      cnt[row] = c;
      inv_deg[row] = 1.0f / (float)(c > 0 ? c : 1);
    }
    return;
  }
  int ab = blk - NROWS;
  if (ab < 512) {
    int id = ab * 256 + threadIdx.x;   // 0 .. 131071
    int which = id >> 16;
    int e = id & 65535;
    int rr = e >> 14, rem = e & 16383, ff = rem >> 7, o = rem & 127;
    const float* srcw = which ? W2 : W1;
    float* dst = which ? W2T : W1T;
    dst[e] = srcw[(rr * FDIM + o) * FDIM + ff];
    return;
  }
  int idx = (ab - 512) * 256 + threadIdx.x;   // 0 .. 511
  int rr = idx >> 7, ff = idx & 127;
  diagM[idx] = M[((size_t)(rr * FDIM + ff)) * FDIM + ff];
}

// ---------------------------------------------------------------------------
// Shared body for both layers: fused CSR gather + GEMM + sigmoid.
// (Unchanged from R7: 4-deep gather proved neutral; kept as-is.)
// ---------------------------------------------------------------------------
struct LSmem {
  float aggL[4][KDIM];                  // 8 KB (first: 16B alignment)
  unsigned short lc[4][N_REL][MAXNZ];   // 4 KB
  float red[4][FDIM];                   // 2 KB
};

__device__ __forceinline__ void layer_body(
    LSmem& S,
    const unsigned short* __restrict__ cols, const int* __restrict__ cnt,
    const float* __restrict__ inv_deg, const float* __restrict__ src,
    const float* __restrict__ BT, float* __restrict__ dst, int n0) {
  {
    int i = threadIdx.x >> 4;       // row slot 0..15
    int t16 = threadIdx.x & 15;
    int nb = i >> 2, r = i & 3;
    int row = r * N_ENT + n0 + nb;
    int c = cnt[row];
    for (int j = t16; j < c; j += 16)
      S.lc[nb][r][j] = cols[(size_t)row * MAXNZ + j];
  }
  __syncthreads();
  {
    int l = threadIdx.x & 31;       // float4 lane
    int g = threadIdx.x >> 5;       // pair group 0..7
    const float* fp = src + l * 4;
#pragma unroll
    for (int q = 0; q < 2; ++q) {
      int pair = g + q * 8;         // 0..15 = nb*4 + r
      int nb = pair >> 2, r = pair & 3;
      int row = r * N_ENT + n0 + nb;
      int c = cnt[row];
      float w = inv_deg[row];
      float ax = 0.f, ay = 0.f, az = 0.f, aw = 0.f;
      int j = 0;
      for (; j + 4 <= c; j += 4) {   // 4 independent loads in flight
        float4 v0 = *(const float4*)(fp + (int)S.lc[nb][r][j] * FDIM);
        float4 v1 = *(const float4*)(fp + (int)S.lc[nb][r][j + 1] * FDIM);
        float4 v2 = *(const float4*)(fp + (int)S.lc[nb][r][j + 2] * FDIM);
        float4 v3 = *(const float4*)(fp + (int)S.lc[nb][r][j + 3] * FDIM);
        ax += (v0.x + v1.x) + (v2.x + v3.x);
        ay += (v0.y + v1.y) + (v2.y + v3.y);
        az += (v0.z + v1.z) + (v2.z + v3.z);
        aw += (v0.w + v1.w) + (v2.w + v3.w);
      }
      for (; j < c; ++j) {           // tail: up to 3 singles
        float4 v = *(const float4*)(fp + (int)S.lc[nb][r][j] * FDIM);
        ax += v.x; ay += v.y; az += v.z; aw += v.w;
      }
      float4 res; res.x = ax * w; res.y = ay * w; res.z = az * w; res.w = aw * w;
      *(float4*)&S.aggL[nb][r * FDIM + l * 4] = res;
    }
  }
  __syncthreads();
  {
    constexpr int KH = KDIM / 2, Ncol = FDIM;
    int o = threadIdx.x & 127;
    int half = threadIdx.x >> 7;
    const float* Bp = BT + (size_t)half * KH * Ncol + o;
    int kbase = half * KH;
    float acc[4] = {0.f, 0.f, 0.f, 0.f};
#pragma unroll 2
    for (int k = 0; k < KH; k += 4) {
      float4 a0 = *(const float4*)&S.aggL[0][kbase + k];
      float4 a1 = *(const float4*)&S.aggL[1][kbase + k];
      float4 a2 = *(const float4*)&S.aggL[2][kbase + k];
      float4 a3 = *(const float4*)&S.aggL[3][kbase + k];
      float b0 = Bp[(size_t)(k + 0) * Ncol];
      float b1 = Bp[(size_t)(k + 1) * Ncol];
      float b2 = Bp[(size_t)(k + 2) * Ncol];
      float b3 = Bp[(size_t)(k + 3) * Ncol];
      acc[0] += a0.x * b0 + a0.y * b1 + a0.z * b2 + a0.w * b3;
      acc[1] += a1.x * b0 + a1.y * b1 + a1.z * b2 + a1.w * b3;
      acc[2] += a2.x * b0 + a2.y * b1 + a2.z * b2 + a2.w * b3;
      acc[3] += a3.x * b0 + a3.y * b1 + a3.z * b2 + a3.w * b3;
    }
    if (half) {
#pragma unroll
      for (int i = 0; i < 4; ++i) S.red[i][o] = acc[i];
    }
    __syncthreads();
    if (!half) {
#pragma unroll
      for (int i = 0; i < 4; ++i) {
        float v = acc[i] + S.red[i][o];
        v = 1.f / (1.f + __expf(-v));
        dst[(size_t)(n0 + i) * Ncol + o] = v;
      }
    }
  }
}

__global__ __launch_bounds__(256) void k_layer1(
    const unsigned short* __restrict__ cols, const int* __restrict__ cnt,
    const float* __restrict__ inv_deg, const float* __restrict__ feat,
    const float* __restrict__ W1T, float* __restrict__ h1) {
  __shared__ __align__(16) LSmem S;
  layer_body(S, cols, cnt, inv_deg, feat, W1T, h1, blockIdx.x * 4);
}

__global__ __launch_bounds__(256) void k_layer2(
    const unsigned short* __restrict__ cols, const int* __restrict__ cnt,
    const float* __restrict__ inv_deg, const float* __restrict__ h1,
    const float* __restrict__ W2T, float* __restrict__ h2) {
  __shared__ __align__(16) LSmem S;
  layer_body(S, cols, cnt, inv_deg, h1, W2T, h2, blockIdx.x * 4);
}

// ---------------------------------------------------------------------------
// K4: diagonal DistMult: out[b] = sum_f h[e1,f] * diagM[rel,f] * h[e2,f].
// One wave per sample, 4 samples per block.
// ---------------------------------------------------------------------------
__global__ __launch_bounds__(256) void k_score(
    const float* __restrict__ h, const float* __restrict__ diagM,
    const int* __restrict__ e1, const int* __restrict__ rel,
    const int* __restrict__ e2, float* __restrict__ out) {
  int wave = threadIdx.x >> 6;
  int lane = threadIdx.x & 63;
  int b = blockIdx.x * 4 + wave;
  int a = e1[b], r = rel[b], c = e2[b];
  const float* hp = h + (size_t)a * FDIM;
  const float* dp = diagM + (size_t)r * FDIM;
  const float* gp = h + (size_t)c * FDIM;
  float v = hp[lane] * dp[lane] * gp[lane]
          + hp[lane + 64] * dp[lane + 64] * gp[lane + 64];
#pragma unroll
  for (int off = 32; off > 0; off >>= 1) v += __shfl_down(v, off, 64);
  if (lane == 0) out[b] = v;
}

// ---------------------------------------------------------------------------
extern "C" void kernel_launch(void* const* d_in, const int* in_sizes, int n_in,
                              void* d_out, int out_size, void* d_ws, size_t ws_size,
                              hipStream_t stream) {
  const float* feat = (const float*)d_in[0];
  const float* adj  = (const float*)d_in[1];
  const float* W1   = (const float*)d_in[2];
  const float* W2   = (const float*)d_in[3];
  const float* M    = (const float*)d_in[4];
  const int* e1     = (const int*)d_in[5];
  const int* rel    = (const int*)d_in[6];
  const int* e2     = (const int*)d_in[7];
  float* out = (float*)d_out;

  char* ws = (char*)d_ws;
  unsigned short* cols = (unsigned short*)(ws);                 // 4 MB
  int*   cnt  = (int*)  (ws + 4194304);                         // 64 KB
  float* inv  = (float*)(ws + 4259840);                         // 64 KB
  float* W1T  = (float*)(ws + 4325376);                         // 256 KB
  float* W2T  = (float*)(ws + 4587520);                         // 256 KB
  float* dM   = (float*)(ws + 4849664);                         // 2 KB
  float* h1   = (float*)(ws + 13500416);                        // 2 MB
  float* h2   = (float*)(ws + 15597568);                        // 2 MB

  // pure adj stream: sparsify -> CSR (+ weight transposes + relmat diag)
  k_sparse<<<NROWS + 514, 256, 0, stream>>>(
      W1, W2, M, adj, W1T, W2T, dM, cols, cnt, inv);
  // layer 1: fused gather(feat) + GEMM(W1T) -> h1
  k_layer1<<<N_ENT / 4, 256, 0, stream>>>(cols, cnt, inv, feat, W1T, h1);
  // layer 2: fused gather(h1) + GEMM(W2T) -> h2
  k_layer2<<<N_ENT / 4, 256, 0, stream>>>(cols, cnt, inv, h1, W2T, h2);
  // diagonal DistMult scores
  k_score<<<BATCH / 4, 256, 0, stream>>>(h2, dM, e1, rel, e2, out);
}

// Round 10
// 409.133 us; speedup vs baseline: 1.0571x; 1.0571x over previous
//
#include <hip/hip_runtime.h>
#include <hip/hip_bf16.h>

#define N_ENT 4096
#define N_REL 4
#define FDIM 128
#define KDIM 512      // N_REL * FDIM
#define MAXNZ 128     // binomial(4096,0.01): mean 41, std 6.4; 128 is >13 sigma
#define BATCH 8192
#define NROWS (N_REL * N_ENT)

typedef float f4v __attribute__((ext_vector_type(4)));

// ---------------------------------------------------------------------------
// K_sparse: PURE adj stream kernel (R6 verified structure, NT RESTORED).
// R9's isolated A/B: NT vs plain on the adj stream = 410.1/411.2 vs 432.5 us.
// NT is protective (-22us): it keeps the 256MB single-use stream from
// allocating in / thrashing L2-L3; the per-iteration 1GiB poison fill sweeps
// L3 regardless, so there is no cross-iteration retention upside to plain
// loads. NT on this stream is mandatory.
//   blocks [0, NROWS): sparsify one adj row: NT coalesced wave-contiguous
//     float4 loads, popc -> 6-step shfl_up scan -> direct global cols writes.
//   blocks [NROWS, NROWS+514): W1/W2 transpose + relmat diag extract.
// ---------------------------------------------------------------------------
__global__ __launch_bounds__(256) void k_sparse(
    const float* __restrict__ W1, const float* __restrict__ W2,
    const float* __restrict__ M, const float* __restrict__ adj,
    float* __restrict__ W1T, float* __restrict__ W2T, float* __restrict__ diagM,
    unsigned short* __restrict__ cols, int* __restrict__ cnt,
    float* __restrict__ inv_deg) {
  int blk = blockIdx.x;
  if (blk < NROWS) {
    int row = blk;               // r*N_ENT + n
    __shared__ int wtot[4];
    int w = threadIdx.x >> 6;    // wave 0..3, owns elements [w*1024, w*1024+1024)
    int l = threadIdx.x & 63;    // lane
    const f4v* rowp = (const f4v*)(adj + (size_t)row * N_ENT);
    unsigned mask = 0;
#pragma unroll
    for (int q = 0; q < 4; ++q) {
      // float4 index w*256 + q*64 + l: lanes consecutive -> 1 KB/wave/load
      f4v v = __builtin_nontemporal_load(rowp + w * 256 + q * 64 + l);
      if (v.x != 0.f) mask |= 1u << (q * 4 + 0);
      if (v.y != 0.f) mask |= 1u << (q * 4 + 1);
      if (v.z != 0.f) mask |= 1u << (q * 4 + 2);
      if (v.w != 0.f) mask |= 1u << (q * 4 + 3);
    }
    int my = __popc(mask);
    // wave-inclusive prefix scan of per-lane counts (6 shfl_up steps)
    int scan = my;
#pragma unroll
    for (int off = 1; off < 64; off <<= 1) {
      int nb = __shfl_up(scan, off, 64);
      if (l >= off) scan += nb;
    }
    if (l == 63) wtot[w] = scan;       // wave total
    int excl = scan - my;              // lane-exclusive prefix within wave
    __syncthreads();
    int wbase = 0, c = 0;
#pragma unroll
    for (int ww = 0; ww < 4; ++ww) {
      int t = wtot[ww];
      if (ww < w) wbase += t;
      c += t;
    }
    if (c > MAXNZ) c = MAXNZ;
    int p = wbase + excl;
    unsigned m = mask;
    unsigned short* cp = cols + (size_t)row * MAXNZ;
    while (m) {
      int b = __ffs(m) - 1;
      m &= m - 1;
      int col = w * 1024 + (b >> 2) * 256 + l * 4 + (b & 3);
      if (p < MAXNZ) cp[p] = (unsigned short)col;
      ++p;
    }
    if (threadIdx.x == 0) {
      cnt[row] = c;
      inv_deg[row] = 1.0f / (float)(c > 0 ? c : 1);
    }
    return;
  }
  int ab = blk - NROWS;
  if (ab < 512) {
    int id = ab * 256 + threadIdx.x;   // 0 .. 131071
    int which = id >> 16;
    int e = id & 65535;
    int rr = e >> 14, rem = e & 16383, ff = rem >> 7, o = rem & 127;
    const float* srcw = which ? W2 : W1;
    float* dst = which ? W2T : W1T;
    dst[e] = srcw[(rr * FDIM + o) * FDIM + ff];
    return;
  }
  int idx = (ab - 512) * 256 + threadIdx.x;   // 0 .. 511
  int rr = idx >> 7, ff = idx & 127;
  diagM[idx] = M[((size_t)(rr * FDIM + ff)) * FDIM + ff];
}

// ---------------------------------------------------------------------------
// Shared body for both layers: fused CSR gather + GEMM + sigmoid.
// (R7-verified: 4-deep gather, agg tile in LDS, 2-way split-K GEMM.)
// ---------------------------------------------------------------------------
struct LSmem {
  float aggL[4][KDIM];                  // 8 KB (first: 16B alignment)
  unsigned short lc[4][N_REL][MAXNZ];   // 4 KB
  float red[4][FDIM];                   // 2 KB
};

__device__ __forceinline__ void layer_body(
    LSmem& S,
    const unsigned short* __restrict__ cols, const int* __restrict__ cnt,
    const float* __restrict__ inv_deg, const float* __restrict__ src,
    const float* __restrict__ BT, float* __restrict__ dst, int n0) {
  {
    int i = threadIdx.x >> 4;       // row slot 0..15
    int t16 = threadIdx.x & 15;
    int nb = i >> 2, r = i & 3;
    int row = r * N_ENT + n0 + nb;
    int c = cnt[row];
    for (int j = t16; j < c; j += 16)
      S.lc[nb][r][j] = cols[(size_t)row * MAXNZ + j];
  }
  __syncthreads();
  {
    int l = threadIdx.x & 31;       // float4 lane
    int g = threadIdx.x >> 5;       // pair group 0..7
    const float* fp = src + l * 4;
#pragma unroll
    for (int q = 0; q < 2; ++q) {
      int pair = g + q * 8;         // 0..15 = nb*4 + r
      int nb = pair >> 2, r = pair & 3;
      int row = r * N_ENT + n0 + nb;
      int c = cnt[row];
      float w = inv_deg[row];
      float ax = 0.f, ay = 0.f, az = 0.f, aw = 0.f;
      int j = 0;
      for (; j + 4 <= c; j += 4) {   // 4 independent loads in flight
        float4 v0 = *(const float4*)(fp + (int)S.lc[nb][r][j] * FDIM);
        float4 v1 = *(const float4*)(fp + (int)S.lc[nb][r][j + 1] * FDIM);
        float4 v2 = *(const float4*)(fp + (int)S.lc[nb][r][j + 2] * FDIM);
        float4 v3 = *(const float4*)(fp + (int)S.lc[nb][r][j + 3] * FDIM);
        ax += (v0.x + v1.x) + (v2.x + v3.x);
        ay += (v0.y + v1.y) + (v2.y + v3.y);
        az += (v0.z + v1.z) + (v2.z + v3.z);
        aw += (v0.w + v1.w) + (v2.w + v3.w);
      }
      for (; j < c; ++j) {           // tail: up to 3 singles
        float4 v = *(const float4*)(fp + (int)S.lc[nb][r][j] * FDIM);
        ax += v.x; ay += v.y; az += v.z; aw += v.w;
      }
      float4 res; res.x = ax * w; res.y = ay * w; res.z = az * w; res.w = aw * w;
      *(float4*)&S.aggL[nb][r * FDIM + l * 4] = res;
    }
  }
  __syncthreads();
  {
    constexpr int KH = KDIM / 2, Ncol = FDIM;
    int o = threadIdx.x & 127;
    int half = threadIdx.x >> 7;
    const float* Bp = BT + (size_t)half * KH * Ncol + o;
    int kbase = half * KH;
    float acc[4] = {0.f, 0.f, 0.f, 0.f};
#pragma unroll 2
    for (int k = 0; k < KH; k += 4) {
      float4 a0 = *(const float4*)&S.aggL[0][kbase + k];
      float4 a1 = *(const float4*)&S.aggL[1][kbase + k];
      float4 a2 = *(const float4*)&S.aggL[2][kbase + k];
      float4 a3 = *(const float4*)&S.aggL[3][kbase + k];
      float b0 = Bp[(size_t)(k + 0) * Ncol];
      float b1 = Bp[(size_t)(k + 1) * Ncol];
      float b2 = Bp[(size_t)(k + 2) * Ncol];
      float b3 = Bp[(size_t)(k + 3) * Ncol];
      acc[0] += a0.x * b0 + a0.y * b1 + a0.z * b2 + a0.w * b3;
      acc[1] += a1.x * b0 + a1.y * b1 + a1.z * b2 + a1.w * b3;
      acc[2] += a2.x * b0 + a2.y * b1 + a2.z * b2 + a2.w * b3;
      acc[3] += a3.x * b0 + a3.y * b1 + a3.z * b2 + a3.w * b3;
    }
    if (half) {
#pragma unroll
      for (int i = 0; i < 4; ++i) S.red[i][o] = acc[i];
    }
    __syncthreads();
    if (!half) {
#pragma unroll
      for (int i = 0; i < 4; ++i) {
        float v = acc[i] + S.red[i][o];
        v = 1.f / (1.f + __expf(-v));
        dst[(size_t)(n0 + i) * Ncol + o] = v;
      }
    }
  }
}

__global__ __launch_bounds__(256) void k_layer1(
    const unsigned short* __restrict__ cols, const int* __restrict__ cnt,
    const float* __restrict__ inv_deg, const float* __restrict__ feat,
    const float* __restrict__ W1T, float* __restrict__ h1) {
  __shared__ __align__(16) LSmem S;
  layer_body(S, cols, cnt, inv_deg, feat, W1T, h1, blockIdx.x * 4);
}

__global__ __launch_bounds__(256) void k_layer2(
    const unsigned short* __restrict__ cols, const int* __restrict__ cnt,
    const float* __restrict__ inv_deg, const float* __restrict__ h1,
    const float* __restrict__ W2T, float* __restrict__ h2) {
  __shared__ __align__(16) LSmem S;
  layer_body(S, cols, cnt, inv_deg, h1, W2T, h2, blockIdx.x * 4);
}

// ---------------------------------------------------------------------------
// K4: diagonal DistMult: out[b] = sum_f h[e1,f] * diagM[rel,f] * h[e2,f].
// One wave per sample, 4 samples per block.
// ---------------------------------------------------------------------------
__global__ __launch_bounds__(256) void k_score(
    const float* __restrict__ h, const float* __restrict__ diagM,
    const int* __restrict__ e1, const int* __restrict__ rel,
    const int* __restrict__ e2, float* __restrict__ out) {
  int wave = threadIdx.x >> 6;
  int lane = threadIdx.x & 63;
  int b = blockIdx.x * 4 + wave;
  int a = e1[b], r = rel[b], c = e2[b];
  const float* hp = h + (size_t)a * FDIM;
  const float* dp = diagM + (size_t)r * FDIM;
  const float* gp = h + (size_t)c * FDIM;
  float v = hp[lane] * dp[lane] * gp[lane]
          + hp[lane + 64] * dp[lane + 64] * gp[lane + 64];
#pragma unroll
  for (int off = 32; off > 0; off >>= 1) v += __shfl_down(v, off, 64);
  if (lane == 0) out[b] = v;
}

// ---------------------------------------------------------------------------
extern "C" void kernel_launch(void* const* d_in, const int* in_sizes, int n_in,
                              void* d_out, int out_size, void* d_ws, size_t ws_size,
                              hipStream_t stream) {
  const float* feat = (const float*)d_in[0];
  const float* adj  = (const float*)d_in[1];
  const float* W1   = (const float*)d_in[2];
  const float* W2   = (const float*)d_in[3];
  const float* M    = (const float*)d_in[4];
  const int* e1     = (const int*)d_in[5];
  const int* rel    = (const int*)d_in[6];
  const int* e2     = (const int*)d_in[7];
  float* out = (float*)d_out;

  char* ws = (char*)d_ws;
  unsigned short* cols = (unsigned short*)(ws);                 // 4 MB
  int*   cnt  = (int*)  (ws + 4194304);                         // 64 KB
  float* inv  = (float*)(ws + 4259840);                         // 64 KB
  float* W1T  = (float*)(ws + 4325376);                         // 256 KB
  float* W2T  = (float*)(ws + 4587520);                         // 256 KB
  float* dM   = (float*)(ws + 4849664);                         // 2 KB
  float* h1   = (float*)(ws + 13500416);                        // 2 MB
  float* h2   = (float*)(ws + 15597568);                        // 2 MB

  // pure adj stream: sparsify -> CSR (+ weight transposes + relmat diag)
  k_sparse<<<NROWS + 514, 256, 0, stream>>>(
      W1, W2, M, adj, W1T, W2T, dM, cols, cnt, inv);
  // layer 1: fused gather(feat) + GEMM(W1T) -> h1
  k_layer1<<<N_ENT / 4, 256, 0, stream>>>(cols, cnt, inv, feat, W1T, h1);
  // layer 2: fused gather(h1) + GEMM(W2T) -> h2
  k_layer2<<<N_ENT / 4, 256, 0, stream>>>(cols, cnt, inv, h1, W2T, h2);
  // diagonal DistMult scores
  k_score<<<BATCH / 4, 256, 0, stream>>>(h2, dM, e1, rel, e2, out);
}